// Round 13
// baseline (101.102 us; speedup 1.0000x reference)
//
#include <hip/hip_runtime.h>

#define BATCH 8192
#define KNB   64
#define EMB   16
#define CHD   16
#define DVD   20
#define H1    64
#define H2    64
#define AH    84
#define IN1   32
#define IN2   132

#define RB 32    // b-rows per K2 block
#define VB 16    // vertices per K2 block

typedef float vf4 __attribute__((ext_vector_type(4)));
typedef unsigned short u16;
typedef u16 u16x8 __attribute__((ext_vector_type(8)));

// LDS table bases (in floats): lang|plat|os|country|carrier|brand|plat_os
#define TB_LANG    0
#define TB_PLAT    1600
#define TB_OS      1664
#define TB_COUNTRY 2464
#define TB_CARRIER 5664
#define TB_BRAND   13664
#define TB_PLATOS  29664
#define TB_TOTAL   34464   // floats = 137.9 KB

// ---------------------------------------------------------------------------
// K1: ALL 7 embedding tables staged in LDS (137.9 KB); 1024-thread blocks,
// 16 waves, each wave owns one (vertex,half) item. Only dense rows + cat rows
// remain on the global path.
//  - o16[w][k][slot]: u16 row*16 offsets (max 16000 < 65536)
//  - nds[w][k]: dense float-offset n*20 (int)
//  - slot map: 0-4 dense(global) | 5-8 lang | 9-12 os | 13-16 country |
//    17-20 carrier | 21-24 brand | 25-28 plat_os | 29-31 plat (29 dbl-duty)
//  - dense lanes: asm-forced 8-deep global float4 batches
//  - one __syncthreads (tables + offsets visibility)
// ---------------------------------------------------------------------------
__global__ __launch_bounds__(1024, 4) void gconv_gather(
    const float* __restrict__ device_dense,
    const float* __restrict__ t0, const float* __restrict__ t1,
    const float* __restrict__ t2, const float* __restrict__ t3,
    const float* __restrict__ t4, const float* __restrict__ t5,
    const float* __restrict__ t6,
    const int* __restrict__ device_cat,
    const int* __restrict__ bot_neibrs,
    const int* __restrict__ normal_neibrs,
    const int* __restrict__ bot_counts,
    const int* __restrict__ normal_counts,
    float* __restrict__ fsum_ws)
{
    const int t    = threadIdx.x;
    const int w    = t >> 6;            // wave 0..15
    const int L    = t & 63;
    const int kk   = L >> 5;            // neighbor parity
    const int slot = L & 31;
    const int item = blockIdx.x * 16 + w;
    const int v    = item >> 1;

    __shared__ alignas(16) float tab[TB_TOTAL];       // 137.9 KB
    __shared__ alignas(16) u16   o16[16][KNB][8];     // 16 KB
    __shared__ int               nds[16][KNB];        // 4 KB

    // ---- stage all 7 tables (8616 float4, 1024 threads -> 9 iters) ------
    for (int i = t; i < 8616; i += 1024) {
        float4 vsrc;
        if (i < 400)       vsrc = ((const float4*)t0)[i];
        else if (i < 416)  vsrc = ((const float4*)t1)[i - 400];
        else if (i < 616)  vsrc = ((const float4*)t2)[i - 416];
        else if (i < 1416) vsrc = ((const float4*)t3)[i - 616];
        else if (i < 3416) vsrc = ((const float4*)t4)[i - 1416];
        else if (i < 7416) vsrc = ((const float4*)t5)[i - 3416];
        else               vsrc = ((const float4*)t6)[i - 7416];
        ((float4*)tab)[i] = vsrc;
    }

    int cnt = (item & 1) ? normal_counts[v] : bot_counts[v];
    cnt = cnt < 1 ? 1 : (cnt > KNB ? KNB : cnt);
    cnt = __builtin_amdgcn_readfirstlane(cnt);

    // ---- prologue: lane L = neighbor L ----------------------------------
    {
        const int* nb = (item & 1) ? normal_neibrs : bot_neibrs;
        int n = 0;
        if (L < cnt) n = nb[v * KNB + L];
        const long cb = (long)n * 7;
        const int4 cA = *(const int4*)(device_cat + cb);      // lang,plat,os,country
        const int4 cB = *(const int4*)(device_cat + cb + 3);  // country,carrier,brand,plat_os
        nds[w][L] = n * DVD;
        u16x8 pk;
        pk[0] = (u16)(cA.x * EMB); pk[1] = (u16)(cA.y * EMB);
        pk[2] = (u16)(cA.z * EMB); pk[3] = (u16)(cA.w * EMB);
        pk[4] = (u16)(cB.y * EMB); pk[5] = (u16)(cB.z * EMB);
        pk[6] = (u16)(cB.w * EMB); pk[7] = 0;
        *(u16x8*)&o16[w][L][0] = pk;
    }
    __syncthreads();   // tables + offsets visible (only barrier)

    // ---- per-lane slot mapping ------------------------------------------
    int base = 0, idx = 0, col = 0, feat = 0;
    const bool isG = (slot < 5);
    if (slot < 5)       { col = 4 * slot;        feat = col; }
    else if (slot < 9)  { base = TB_LANG;    idx = 0; col = 4 * (slot - 5);  feat = 20  + col; }
    else if (slot < 13) { base = TB_OS;      idx = 2; col = 4 * (slot - 9);  feat = 52  + col; }
    else if (slot < 17) { base = TB_COUNTRY; idx = 3; col = 4 * (slot - 13); feat = 68  + col; }
    else if (slot < 21) { base = TB_CARRIER; idx = 4; col = 4 * (slot - 17); feat = 84  + col; }
    else if (slot < 25) { base = TB_BRAND;   idx = 5; col = 4 * (slot - 21); feat = 100 + col; }
    else if (slot < 29) { base = TB_PLATOS;  idx = 6; col = 4 * (slot - 25); feat = 116 + col; }
    else                { base = TB_PLAT;    idx = 1; col = 4 * (slot - 29); feat = 36  + col; }

    // ---- gather: 8-deep batches over neighbor pairs ---------------------
    vf4 acc  = {0.f, 0.f, 0.f, 0.f};
    vf4 acc2 = {0.f, 0.f, 0.f, 0.f};
    const int passes = (cnt + 1) >> 1;            // <= 32
    for (int pc = 0; pc < passes; pc += 8) {
        if (isG) {
            int o[8];
            #pragma unroll
            for (int j = 0; j < 8; ++j)
                o[j] = nds[w][2 * (pc + j) + kk];       // pc+j <= 31 always
            vf4 val[8];
            #pragma unroll
            for (int j = 0; j < 8; ++j) {
                const float* ap = device_dense + o[j] + col;
                asm volatile("global_load_dwordx4 %0, %1, off"
                             : "=v"(val[j]) : "v"(ap) : "memory");
            }
            asm volatile("s_waitcnt vmcnt(0)" ::: "memory");
            __builtin_amdgcn_sched_barrier(0);
            #pragma unroll
            for (int j = 0; j < 8; ++j) {
                const float m = (2 * (pc + j) + kk < cnt) ? 1.f : 0.f;
                acc[0] = fmaf(m, val[j][0], acc[0]);
                acc[1] = fmaf(m, val[j][1], acc[1]);
                acc[2] = fmaf(m, val[j][2], acc[2]);
                acc[3] = fmaf(m, val[j][3], acc[3]);
            }
        } else {
            #pragma unroll
            for (int j = 0; j < 8; ++j) {
                const int k = 2 * (pc + j) + kk;
                const float m = (k < cnt) ? 1.f : 0.f;
                const int row = o16[w][k][idx];
                const float4 lv = *(const float4*)&tab[base + row + col];
                acc[0] = fmaf(m, lv.x, acc[0]);
                acc[1] = fmaf(m, lv.y, acc[1]);
                acc[2] = fmaf(m, lv.z, acc[2]);
                acc[3] = fmaf(m, lv.w, acc[3]);
                if (slot == 29) {                       // plat cols 12..15
                    const float4 l2 = *(const float4*)&tab[base + row + 12];
                    acc2[0] = fmaf(m, l2.x, acc2[0]);
                    acc2[1] = fmaf(m, l2.y, acc2[1]);
                    acc2[2] = fmaf(m, l2.z, acc2[2]);
                    acc2[3] = fmaf(m, l2.w, acc2[3]);
                }
            }
        }
    }

    // ---- pair-combine (L <-> L^32) --------------------------------------
    acc[0] += __shfl_xor(acc[0], 32, 64);
    acc[1] += __shfl_xor(acc[1], 32, 64);
    acc[2] += __shfl_xor(acc[2], 32, 64);
    acc[3] += __shfl_xor(acc[3], 32, 64);
    if (slot == 29) {
        acc2[0] += __shfl_xor(acc2[0], 32, 64);
        acc2[1] += __shfl_xor(acc2[1], 32, 64);
        acc2[2] += __shfl_xor(acc2[2], 32, 64);
        acc2[3] += __shfl_xor(acc2[3], 32, 64);
    }

    // ---- stores ----------------------------------------------------------
    if (L < 32)
        *(float4*)(fsum_ws + (size_t)item * IN2 + feat) =
            make_float4(acc[0], acc[1], acc[2], acc[3]);
    if (L == 29)
        *(float4*)(fsum_ws + (size_t)item * IN2 + 48) =
            make_float4(acc2[0], acc2[1], acc2[2], acc2[3]);
}
#undef TB_PLAT
#define TB_PLAT 1600

// ---------------------------------------------------------------------------
// K2: all dense math for 32 b-rows (16 vertices) per block, 256 threads.
// ---------------------------------------------------------------------------
__global__ __launch_bounds__(256) void gconv_dense(
    const float* __restrict__ channel_dense,
    const float* __restrict__ channel_id_emb,
    const float* __restrict__ W_agg,  const float* __restrict__ b_agg,
    const float* __restrict__ W_self, const float* __restrict__ b_self,
    const float* __restrict__ W_attn, const float* __restrict__ b_attn,
    const float* __restrict__ W_attn2,
    const int* __restrict__ channel_ids,
    const int* __restrict__ vertices,
    const int* __restrict__ bot_counts,
    const int* __restrict__ normal_counts,
    const float* __restrict__ fsum_ws,
    float* __restrict__ out)
{
    const int blk = blockIdx.x;
    const int b0  = blk * RB;
    const int v0  = blk * VB;
    const int t   = threadIdx.x;

    __shared__ alignas(16) float fs[RB][IN2];
    __shared__ alignas(16) float chvs[VB][IN1];
    __shared__ alignas(16) float hs[RB][H2];
    __shared__ float u_lds[AH][RB + 1];
    __shared__ float sarr[RB];
    __shared__ float cinv[RB];

    for (int idx = t; idx < RB * IN2 / 4; idx += 256) {
        const float4 vv = *(const float4*)(fsum_ws + (size_t)b0 * IN2 + idx * 4);
        *(float4*)&((float*)fs)[idx * 4] = vv;
    }
    if (t < RB) {
        const int b = b0 + t;
        const int v = b >> 1;
        int c = (b & 1) ? normal_counts[v] : bot_counts[v];
        c = (c > KNB) ? KNB : ((c < 1) ? 1 : c);
        cinv[t] = 1.0f / (float)c;
    }
    if (t < 128) {
        const int vx = t >> 3, q = t & 7;
        const int vert = vertices[v0 + vx];
        const float* src = (q < 4)
            ? channel_dense  + (size_t)vert * CHD + q * 4
            : channel_id_emb + (size_t)channel_ids[vert] * EMB + (q - 4) * 4;
        *(float4*)&chvs[vx][q * 4] = *(const float4*)src;
    }
    __syncthreads();

    {
        const int w = t >> 6, lane = t & 63;
        const int r0 = w * 8;
        float acc[8] = {0.f, 0.f, 0.f, 0.f, 0.f, 0.f, 0.f, 0.f};
        #pragma unroll 4
        for (int f = 0; f < IN2; ++f) {
            const float wv = W_agg[f * H2 + lane];
            #pragma unroll
            for (int r = 0; r < 8; ++r)
                acc[r] = fmaf(fs[r0 + r][f], wv, acc[r]);
        }
        const float bb = b_agg[lane];
        #pragma unroll
        for (int r = 0; r < 8; ++r)
            hs[r0 + r][lane] = fmaf(acc[r], cinv[r0 + r], bb);
    }
    __syncthreads();

    if (t < 2 * AH) {
        const int rg = (t >= AH) ? 1 : 0;
        const int aa = t - AH * rg;
        const int r0 = rg * 16;
        float acc[16];
        #pragma unroll
        for (int r = 0; r < 16; ++r) acc[r] = 0.f;
        #pragma unroll 2
        for (int f = 0; f < H2; ++f) {
            const float wv = W_attn[f * AH + aa];
            #pragma unroll
            for (int r = 0; r < 16; ++r)
                acc[r] = fmaf(hs[r0 + r][f], wv, acc[r]);
        }
        #pragma unroll 2
        for (int f = 0; f < IN1; ++f) {
            const float wv = W_attn[(H2 + f) * AH + aa];
            #pragma unroll
            for (int r = 0; r < 16; ++r)
                acc[r] = fmaf(chvs[(r0 + r) >> 1][f], wv, acc[r]);
        }
        const float ba = b_attn[aa], w2 = W_attn2[aa];
        #pragma unroll
        for (int r = 0; r < 16; ++r)
            u_lds[aa][r0 + r] = fmaxf(acc[r] + ba, 0.f) * w2;
    }
    __syncthreads();

    if (t < RB) {
        float s = 0.f;
        #pragma unroll 4
        for (int aa = 0; aa < AH; ++aa) s += u_lds[aa][t];
        sarr[t] = s;
    }
    __syncthreads();

    {
        const int vl = t >> 4;
        const int c8 = (t & 15) * 8;
        const float s0 = sarr[2 * vl], s1 = sarr[2 * vl + 1];
        const float mm = fmaxf(s0, s1);
        const float e0 = __expf(s0 - mm), e1 = __expf(s1 - mm);
        const float rs = 1.0f / (e0 + e1);
        const float a0 = e0 * rs, a1 = e1 * rs;
        float o[8];
        if (c8 < H2) {
            #pragma unroll
            for (int c = 0; c < 8; ++c)
                o[c] = fmaxf(a0 * hs[2 * vl][c8 + c] + a1 * hs[2 * vl + 1][c8 + c], 0.f);
        } else {
            const int cs = c8 - H2;
            float accS[8];
            #pragma unroll
            for (int c = 0; c < 8; ++c) accS[c] = b_self[cs + c];
            #pragma unroll 4
            for (int f = 0; f < IN1; ++f) {
                const float xv = chvs[vl][f];
                const float4 wa = *(const float4*)(W_self + f * H1 + cs);
                const float4 wb = *(const float4*)(W_self + f * H1 + cs + 4);
                accS[0] = fmaf(xv, wa.x, accS[0]);
                accS[1] = fmaf(xv, wa.y, accS[1]);
                accS[2] = fmaf(xv, wa.z, accS[2]);
                accS[3] = fmaf(xv, wa.w, accS[3]);
                accS[4] = fmaf(xv, wb.x, accS[4]);
                accS[5] = fmaf(xv, wb.y, accS[5]);
                accS[6] = fmaf(xv, wb.z, accS[6]);
                accS[7] = fmaf(xv, wb.w, accS[7]);
            }
            #pragma unroll
            for (int c = 0; c < 8; ++c) o[c] = fmaxf(accS[c], 0.f);
        }
        float4* op = (float4*)(out + (size_t)(v0 + vl) * (H1 + H2) + c8);
        op[0] = make_float4(o[0], o[1], o[2], o[3]);
        op[1] = make_float4(o[4], o[5], o[6], o[7]);
    }
}

extern "C" void kernel_launch(void* const* d_in, const int* in_sizes, int n_in,
                              void* d_out, int out_size, void* d_ws, size_t ws_size,
                              hipStream_t stream) {
    const float* channel_dense  = (const float*)d_in[0];
    const float* device_dense   = (const float*)d_in[1];
    const float* channel_id_emb = (const float*)d_in[2];
    const float* lang_emb       = (const float*)d_in[3];
    const float* plat_emb       = (const float*)d_in[4];
    const float* os_emb         = (const float*)d_in[5];
    const float* country_emb    = (const float*)d_in[6];
    const float* carrier_emb    = (const float*)d_in[7];
    const float* brand_emb      = (const float*)d_in[8];
    const float* plat_os_emb    = (const float*)d_in[9];
    const float* W_agg          = (const float*)d_in[10];
    const float* b_agg          = (const float*)d_in[11];
    const float* W_self         = (const float*)d_in[12];
    const float* b_self         = (const float*)d_in[13];
    const float* W_attn         = (const float*)d_in[14];
    const float* b_attn         = (const float*)d_in[15];
    const float* W_attn2        = (const float*)d_in[16];
    // d_in[17] = b_attn2: zero + cancels in 2-way softmax, unused
    const int* channel_ids   = (const int*)d_in[18];
    const int* device_cat    = (const int*)d_in[19];
    const int* vertices      = (const int*)d_in[20];
    const int* bot_neibrs    = (const int*)d_in[21];
    const int* normal_neibrs = (const int*)d_in[22];
    const int* bot_counts    = (const int*)d_in[23];
    const int* normal_counts = (const int*)d_in[24];

    float* fsum_ws = (float*)d_ws;   // [16384][132] = 8.65 MB
    float* out     = (float*)d_out;

    gconv_gather<<<dim3(2 * BATCH / 16), dim3(1024), 0, stream>>>(
        device_dense, lang_emb, plat_emb, os_emb, country_emb, carrier_emb,
        brand_emb, plat_os_emb, device_cat, bot_neibrs, normal_neibrs,
        bot_counts, normal_counts, fsum_ws);

    gconv_dense<<<dim3(2 * BATCH / RB), dim3(256), 0, stream>>>(
        channel_dense, channel_id_emb, W_agg, b_agg, W_self, b_self,
        W_attn, b_attn, W_attn2, channel_ids, vertices,
        bot_counts, normal_counts, fsum_ws, out);
}

// Round 14
// 86.512 us; speedup vs baseline: 1.1687x; 1.1687x over previous
//
#include <hip/hip_runtime.h>

#define BATCH 8192
#define KNB   64
#define EMB   16
#define CHD   16
#define DVD   20
#define H1    64
#define H2    64
#define AH    84
#define IN1   32
#define IN2   132

#define RB 32    // b-rows per K2 block
#define VB 16    // vertices per K2 block

typedef float vf4 __attribute__((ext_vector_type(4)));
typedef unsigned short u16;
typedef u16 u16x8 __attribute__((ext_vector_type(8)));

// LDS table bases (floats): lang | plat | os | country
#define TB_LANG    0
#define TB_PLAT    1600
#define TB_OS      1664
#define TB_COUNTRY 2464
#define TB_TOTAL   5664    // 22.7 KB

// ---------------------------------------------------------------------------
// K1: 4096 blocks x 4 waves; each WAVE owns one (vertex,half) item (R12 base).
//  - lang/plat/os/country staged in LDS (22.7 KB)
//  - u16 offset table (row*16 fits u16 for all 7 tables) + int dense offsets
//    -> ~27.8 KB LDS total -> 5 blocks/CU (20 waves)
//  - slot map: 0-4 dense G | 5-8 carrier G | 9-12 brand G | 13-16 plat_os G |
//    17-20 lang L | 21-24 os L | 25-28 country L | 29-31 plat L (29 dbl-duty)
//  - gather in chunks of 4 (less dead-load tail than 8; depth proven moot)
//  - asm-forced 4-deep global float4 batches; one __syncthreads total
// ---------------------------------------------------------------------------
__global__ __launch_bounds__(256, 5) void gconv_gather(
    const float* __restrict__ device_dense,
    const float* __restrict__ t0, const float* __restrict__ t1,
    const float* __restrict__ t2, const float* __restrict__ t3,
    const float* __restrict__ t4, const float* __restrict__ t5,
    const float* __restrict__ t6,
    const int* __restrict__ device_cat,
    const int* __restrict__ bot_neibrs,
    const int* __restrict__ normal_neibrs,
    const int* __restrict__ bot_counts,
    const int* __restrict__ normal_counts,
    float* __restrict__ fsum_ws)
{
    const int t    = threadIdx.x;
    const int w    = t >> 6;
    const int L    = t & 63;
    const int kk   = L >> 5;            // neighbor parity
    const int slot = L & 31;
    const int item = blockIdx.x * 4 + w;
    const int v    = item >> 1;

    __shared__ alignas(16) float tab[TB_TOTAL];    // 22.7 KB
    __shared__ alignas(16) u16   o16[4][KNB][8];   // 4 KB
    __shared__ int               nds[4][KNB];      // 1 KB

    // ---- stage LDS tables: lang(400 f4) plat(16) os(200) country(800) ---
    for (int i = t; i < 1416; i += 256) {
        float4 vsrc;
        if (i < 400)      vsrc = ((const float4*)t0)[i];
        else if (i < 416) vsrc = ((const float4*)t1)[i - 400];
        else if (i < 616) vsrc = ((const float4*)t2)[i - 416];
        else              vsrc = ((const float4*)t3)[i - 616];
        ((float4*)tab)[i] = vsrc;
    }

    int cnt = (item & 1) ? normal_counts[v] : bot_counts[v];
    cnt = cnt < 1 ? 1 : (cnt > KNB ? KNB : cnt);
    cnt = __builtin_amdgcn_readfirstlane(cnt);

    // ---- prologue: lane L = neighbor L (masked lanes use hot row 0) -----
    {
        const int* nb = (item & 1) ? normal_neibrs : bot_neibrs;
        int n = 0;
        if (L < cnt) n = nb[v * KNB + L];
        const long cb = (long)n * 7;
        const int4 cA = *(const int4*)(device_cat + cb);      // lang,plat,os,country
        const int4 cB = *(const int4*)(device_cat + cb + 3);  // country,carrier,brand,plat_os
        nds[w][L] = n * DVD;
        u16x8 pk;
        pk[0] = (u16)(cA.x * EMB); pk[1] = (u16)(cA.y * EMB);
        pk[2] = (u16)(cA.z * EMB); pk[3] = (u16)(cA.w * EMB);
        pk[4] = (u16)(cB.y * EMB); pk[5] = (u16)(cB.z * EMB);
        pk[6] = (u16)(cB.w * EMB); pk[7] = 0;
        *(u16x8*)&o16[w][L][0] = pk;
    }
    __syncthreads();   // tables + offsets visible (only barrier)

    // ---- per-lane slot mapping (reference feature order) ----------------
    const float* P = device_dense;
    int idx = 0, lbase = 0, col, feat;
    const bool isG     = (slot < 17);
    const bool isDense = (slot < 5);
    if (slot < 5)       {                 col = 4 * slot;        feat = col; }
    else if (slot < 9)  { P = t4; idx = 4; col = 4 * (slot - 5);  feat = 84  + col; }
    else if (slot < 13) { P = t5; idx = 5; col = 4 * (slot - 9);  feat = 100 + col; }
    else if (slot < 17) { P = t6; idx = 6; col = 4 * (slot - 13); feat = 116 + col; }
    else if (slot < 21) { lbase = TB_LANG;    idx = 0; col = 4 * (slot - 17); feat = 20 + col; }
    else if (slot < 25) { lbase = TB_OS;      idx = 2; col = 4 * (slot - 21); feat = 52 + col; }
    else if (slot < 29) { lbase = TB_COUNTRY; idx = 3; col = 4 * (slot - 25); feat = 68 + col; }
    else                { lbase = TB_PLAT;    idx = 1; col = 4 * (slot - 29); feat = 36 + col; }

    // ---- gather: chunks of 4 neighbor-pairs -----------------------------
    vf4 acc  = {0.f, 0.f, 0.f, 0.f};
    vf4 acc2 = {0.f, 0.f, 0.f, 0.f};
    const int passes = (cnt + 1) >> 1;            // <= 32
    for (int pc = 0; pc < passes; pc += 4) {
        if (isG) {
            int o[4];
            #pragma unroll
            for (int j = 0; j < 4; ++j) {
                const int k = 2 * (pc + j) + kk;          // <= 63 always
                o[j] = isDense ? nds[w][k] : (int)o16[w][k][idx];
            }
            vf4 val[4];
            #pragma unroll
            for (int j = 0; j < 4; ++j) {
                const float* ap = P + o[j] + col;
                asm volatile("global_load_dwordx4 %0, %1, off"
                             : "=v"(val[j]) : "v"(ap) : "memory");
            }
            asm volatile("s_waitcnt vmcnt(0)" ::: "memory");
            __builtin_amdgcn_sched_barrier(0);
            #pragma unroll
            for (int j = 0; j < 4; ++j) {
                const float m = (2 * (pc + j) + kk < cnt) ? 1.f : 0.f;
                acc[0] = fmaf(m, val[j][0], acc[0]);
                acc[1] = fmaf(m, val[j][1], acc[1]);
                acc[2] = fmaf(m, val[j][2], acc[2]);
                acc[3] = fmaf(m, val[j][3], acc[3]);
            }
        } else {
            #pragma unroll
            for (int j = 0; j < 4; ++j) {
                const int k = 2 * (pc + j) + kk;
                const float m = (k < cnt) ? 1.f : 0.f;
                const int row = o16[w][k][idx];
                const float4 lv = *(const float4*)&tab[lbase + row + col];
                acc[0] = fmaf(m, lv.x, acc[0]);
                acc[1] = fmaf(m, lv.y, acc[1]);
                acc[2] = fmaf(m, lv.z, acc[2]);
                acc[3] = fmaf(m, lv.w, acc[3]);
                if (slot == 29) {                       // plat cols 12..15
                    const float4 l2 = *(const float4*)&tab[lbase + row + 12];
                    acc2[0] = fmaf(m, l2.x, acc2[0]);
                    acc2[1] = fmaf(m, l2.y, acc2[1]);
                    acc2[2] = fmaf(m, l2.z, acc2[2]);
                    acc2[3] = fmaf(m, l2.w, acc2[3]);
                }
            }
        }
    }

    // ---- pair-combine (L <-> L^32) --------------------------------------
    acc[0] += __shfl_xor(acc[0], 32, 64);
    acc[1] += __shfl_xor(acc[1], 32, 64);
    acc[2] += __shfl_xor(acc[2], 32, 64);
    acc[3] += __shfl_xor(acc[3], 32, 64);
    if (slot == 29) {
        acc2[0] += __shfl_xor(acc2[0], 32, 64);
        acc2[1] += __shfl_xor(acc2[1], 32, 64);
        acc2[2] += __shfl_xor(acc2[2], 32, 64);
        acc2[3] += __shfl_xor(acc2[3], 32, 64);
    }

    // ---- stores ----------------------------------------------------------
    if (L < 32)
        *(float4*)(fsum_ws + (size_t)item * IN2 + feat) =
            make_float4(acc[0], acc[1], acc[2], acc[3]);
    if (L == 29)
        *(float4*)(fsum_ws + (size_t)item * IN2 + 48) =
            make_float4(acc2[0], acc2[1], acc2[2], acc2[3]);
}

// ---------------------------------------------------------------------------
// K2: all dense math for 32 b-rows (16 vertices) per block, 256 threads.
// ---------------------------------------------------------------------------
__global__ __launch_bounds__(256) void gconv_dense(
    const float* __restrict__ channel_dense,
    const float* __restrict__ channel_id_emb,
    const float* __restrict__ W_agg,  const float* __restrict__ b_agg,
    const float* __restrict__ W_self, const float* __restrict__ b_self,
    const float* __restrict__ W_attn, const float* __restrict__ b_attn,
    const float* __restrict__ W_attn2,
    const int* __restrict__ channel_ids,
    const int* __restrict__ vertices,
    const int* __restrict__ bot_counts,
    const int* __restrict__ normal_counts,
    const float* __restrict__ fsum_ws,
    float* __restrict__ out)
{
    const int blk = blockIdx.x;
    const int b0  = blk * RB;
    const int v0  = blk * VB;
    const int t   = threadIdx.x;

    __shared__ alignas(16) float fs[RB][IN2];
    __shared__ alignas(16) float chvs[VB][IN1];
    __shared__ alignas(16) float hs[RB][H2];
    __shared__ float u_lds[AH][RB + 1];
    __shared__ float sarr[RB];
    __shared__ float cinv[RB];

    for (int idx = t; idx < RB * IN2 / 4; idx += 256) {
        const float4 vv = *(const float4*)(fsum_ws + (size_t)b0 * IN2 + idx * 4);
        *(float4*)&((float*)fs)[idx * 4] = vv;
    }
    if (t < RB) {
        const int b = b0 + t;
        const int v = b >> 1;
        int c = (b & 1) ? normal_counts[v] : bot_counts[v];
        c = (c > KNB) ? KNB : ((c < 1) ? 1 : c);
        cinv[t] = 1.0f / (float)c;
    }
    if (t < 128) {
        const int vx = t >> 3, q = t & 7;
        const int vert = vertices[v0 + vx];
        const float* src = (q < 4)
            ? channel_dense  + (size_t)vert * CHD + q * 4
            : channel_id_emb + (size_t)channel_ids[vert] * EMB + (q - 4) * 4;
        *(float4*)&chvs[vx][q * 4] = *(const float4*)src;
    }
    __syncthreads();

    {
        const int w = t >> 6, lane = t & 63;
        const int r0 = w * 8;
        float acc[8] = {0.f, 0.f, 0.f, 0.f, 0.f, 0.f, 0.f, 0.f};
        #pragma unroll 4
        for (int f = 0; f < IN2; ++f) {
            const float wv = W_agg[f * H2 + lane];
            #pragma unroll
            for (int r = 0; r < 8; ++r)
                acc[r] = fmaf(fs[r0 + r][f], wv, acc[r]);
        }
        const float bb = b_agg[lane];
        #pragma unroll
        for (int r = 0; r < 8; ++r)
            hs[r0 + r][lane] = fmaf(acc[r], cinv[r0 + r], bb);
    }
    __syncthreads();

    if (t < 2 * AH) {
        const int rg = (t >= AH) ? 1 : 0;
        const int aa = t - AH * rg;
        const int r0 = rg * 16;
        float acc[16];
        #pragma unroll
        for (int r = 0; r < 16; ++r) acc[r] = 0.f;
        #pragma unroll 2
        for (int f = 0; f < H2; ++f) {
            const float wv = W_attn[f * AH + aa];
            #pragma unroll
            for (int r = 0; r < 16; ++r)
                acc[r] = fmaf(hs[r0 + r][f], wv, acc[r]);
        }
        #pragma unroll 2
        for (int f = 0; f < IN1; ++f) {
            const float wv = W_attn[(H2 + f) * AH + aa];
            #pragma unroll
            for (int r = 0; r < 16; ++r)
                acc[r] = fmaf(chvs[(r0 + r) >> 1][f], wv, acc[r]);
        }
        const float ba = b_attn[aa], w2 = W_attn2[aa];
        #pragma unroll
        for (int r = 0; r < 16; ++r)
            u_lds[aa][r0 + r] = fmaxf(acc[r] + ba, 0.f) * w2;
    }
    __syncthreads();

    if (t < RB) {
        float s = 0.f;
        #pragma unroll 4
        for (int aa = 0; aa < AH; ++aa) s += u_lds[aa][t];
        sarr[t] = s;
    }
    __syncthreads();

    {
        const int vl = t >> 4;
        const int c8 = (t & 15) * 8;
        const float s0 = sarr[2 * vl], s1 = sarr[2 * vl + 1];
        const float mm = fmaxf(s0, s1);
        const float e0 = __expf(s0 - mm), e1 = __expf(s1 - mm);
        const float rs = 1.0f / (e0 + e1);
        const float a0 = e0 * rs, a1 = e1 * rs;
        float o[8];
        if (c8 < H2) {
            #pragma unroll
            for (int c = 0; c < 8; ++c)
                o[c] = fmaxf(a0 * hs[2 * vl][c8 + c] + a1 * hs[2 * vl + 1][c8 + c], 0.f);
        } else {
            const int cs = c8 - H2;
            float accS[8];
            #pragma unroll
            for (int c = 0; c < 8; ++c) accS[c] = b_self[cs + c];
            #pragma unroll 4
            for (int f = 0; f < IN1; ++f) {
                const float xv = chvs[vl][f];
                const float4 wa = *(const float4*)(W_self + f * H1 + cs);
                const float4 wb = *(const float4*)(W_self + f * H1 + cs + 4);
                accS[0] = fmaf(xv, wa.x, accS[0]);
                accS[1] = fmaf(xv, wa.y, accS[1]);
                accS[2] = fmaf(xv, wa.z, accS[2]);
                accS[3] = fmaf(xv, wa.w, accS[3]);
                accS[4] = fmaf(xv, wb.x, accS[4]);
                accS[5] = fmaf(xv, wb.y, accS[5]);
                accS[6] = fmaf(xv, wb.z, accS[6]);
                accS[7] = fmaf(xv, wb.w, accS[7]);
            }
            #pragma unroll
            for (int c = 0; c < 8; ++c) o[c] = fmaxf(accS[c], 0.f);
        }
        float4* op = (float4*)(out + (size_t)(v0 + vl) * (H1 + H2) + c8);
        op[0] = make_float4(o[0], o[1], o[2], o[3]);
        op[1] = make_float4(o[4], o[5], o[6], o[7]);
    }
}

extern "C" void kernel_launch(void* const* d_in, const int* in_sizes, int n_in,
                              void* d_out, int out_size, void* d_ws, size_t ws_size,
                              hipStream_t stream) {
    const float* channel_dense  = (const float*)d_in[0];
    const float* device_dense   = (const float*)d_in[1];
    const float* channel_id_emb = (const float*)d_in[2];
    const float* lang_emb       = (const float*)d_in[3];
    const float* plat_emb       = (const float*)d_in[4];
    const float* os_emb         = (const float*)d_in[5];
    const float* country_emb    = (const float*)d_in[6];
    const float* carrier_emb    = (const float*)d_in[7];
    const float* brand_emb      = (const float*)d_in[8];
    const float* plat_os_emb    = (const float*)d_in[9];
    const float* W_agg          = (const float*)d_in[10];
    const float* b_agg          = (const float*)d_in[11];
    const float* W_self         = (const float*)d_in[12];
    const float* b_self         = (const float*)d_in[13];
    const float* W_attn         = (const float*)d_in[14];
    const float* b_attn         = (const float*)d_in[15];
    const float* W_attn2        = (const float*)d_in[16];
    // d_in[17] = b_attn2: zero + cancels in 2-way softmax, unused
    const int* channel_ids   = (const int*)d_in[18];
    const int* device_cat    = (const int*)d_in[19];
    const int* vertices      = (const int*)d_in[20];
    const int* bot_neibrs    = (const int*)d_in[21];
    const int* normal_neibrs = (const int*)d_in[22];
    const int* bot_counts    = (const int*)d_in[23];
    const int* normal_counts = (const int*)d_in[24];

    float* fsum_ws = (float*)d_ws;   // [16384][132] = 8.65 MB
    float* out     = (float*)d_out;

    gconv_gather<<<dim3(2 * BATCH / 4), dim3(256), 0, stream>>>(
        device_dense, lang_emb, plat_emb, os_emb, country_emb, carrier_emb,
        brand_emb, plat_os_emb, device_cat, bot_neibrs, normal_neibrs,
        bot_counts, normal_counts, fsum_ws);

    gconv_dense<<<dim3(2 * BATCH / RB), dim3(256), 0, stream>>>(
        channel_dense, channel_id_emb, W_agg, b_agg, W_self, b_self,
        W_attn, b_attn, W_attn2, channel_ids, vertices,
        bot_counts, normal_counts, fsum_ws, out);
}

// Round 15
// 71.963 us; speedup vs baseline: 1.4049x; 1.2022x over previous
//
#include <hip/hip_runtime.h>

#define BATCH 8192
#define KNB   64
#define EMB   16
#define CHD   16
#define DVD   20
#define H1    64
#define H2    64
#define AH    84
#define IN1   32
#define IN2   132

#define RB 32    // b-rows per K2 block
#define VB 16    // vertices per K2 block

typedef float vf4 __attribute__((ext_vector_type(4)));

// ---------------------------------------------------------------------------
// K1 (best known, R12): 4096 blocks x 4 waves; each WAVE owns one item.
//  - lang/plat/os staged in LDS (9.9 KB): global segs/instr 18.5 -> ~12
//  - slot map: 21 global lanes (dense5, country4, carrier4, brand4, plat_os4)
//    + 11 LDS lanes (lang4, os4, plat3; lane 29 double-duty for plat cols
//    12..15) -- no separate 33rd-slot global pass
//  - single __syncthreads (table visibility); ofs is wave-private
//  - asm-forced 8-deep global float4 batches
//  - 18 KB LDS + launch_bounds(256,6)
//  Request-wall arithmetic: ~350 segs/item x 64 items/CU x ~6.5 cyc ≈ 58 µs —
//  this config achieves it; all segment-reduction variants paid more in
//  occupancy/conflicts (R13/R14), depth/MLP proven moot (R10).
// ---------------------------------------------------------------------------
__global__ __launch_bounds__(256, 6) void gconv_gather(
    const float* __restrict__ device_dense,
    const float* __restrict__ t0, const float* __restrict__ t1,
    const float* __restrict__ t2, const float* __restrict__ t3,
    const float* __restrict__ t4, const float* __restrict__ t5,
    const float* __restrict__ t6,
    const int* __restrict__ device_cat,
    const int* __restrict__ bot_neibrs,
    const int* __restrict__ normal_neibrs,
    const int* __restrict__ bot_counts,
    const int* __restrict__ normal_counts,
    float* __restrict__ fsum_ws)
{
    const int t    = threadIdx.x;
    const int w    = t >> 6;
    const int L    = t & 63;
    const int kk   = L >> 5;            // neighbor parity
    const int slot = L & 31;
    const int item = blockIdx.x * 4 + w;
    const int v    = item >> 1;

    __shared__ alignas(16) float lds_tab[2464];      // lang|plat|os, 9.9 KB
    __shared__ alignas(16) int   ofs[4][KNB][8];     // wave-private, 8 KB

    // ---- stage small tables: lang(400 f4) plat(16) os(200) --------------
    for (int i = t; i < 616; i += 256) {
        float4 vsrc;
        if (i < 400)      vsrc = ((const float4*)t0)[i];
        else if (i < 416) vsrc = ((const float4*)t1)[i - 400];
        else              vsrc = ((const float4*)t2)[i - 416];
        ((float4*)lds_tab)[i] = vsrc;
    }

    int cnt = (item & 1) ? normal_counts[v] : bot_counts[v];
    cnt = cnt < 1 ? 1 : (cnt > KNB ? KNB : cnt);
    cnt = __builtin_amdgcn_readfirstlane(cnt);

    // ---- prologue: lane L = neighbor L (masked lanes use hot row 0) -----
    {
        const int* nb = (item & 1) ? normal_neibrs : bot_neibrs;
        int n = 0;
        if (L < cnt) n = nb[v * KNB + L];
        const long cb = (long)n * 7;
        const int4 cA = *(const int4*)(device_cat + cb);      // c0..c3
        const int4 cB = *(const int4*)(device_cat + cb + 3);  // c3..c6
        *(int4*)&ofs[w][L][0] = make_int4(n * DVD, cA.x * EMB,
                                          1600 + cA.y * EMB, 1664 + cA.z * EMB);
        *(int4*)&ofs[w][L][4] = make_int4(cA.w * EMB, cB.y * EMB,
                                          cB.z * EMB, cB.w * EMB);
    }
    __syncthreads();   // tables + ofs visible (only barrier)

    // ---- per-lane slot mapping ------------------------------------------
    const float* P = device_dense;
    int oIdx, col, feat;
    if (slot < 5)       { P = device_dense; oIdx = 0; col = 4 * slot;  feat = col; }
    else if (slot < 9)  { P = t3; oIdx = 4; col = 4 * (slot - 5);  feat = 68  + col; }
    else if (slot < 13) { P = t4; oIdx = 5; col = 4 * (slot - 9);  feat = 84  + col; }
    else if (slot < 17) { P = t5; oIdx = 6; col = 4 * (slot - 13); feat = 100 + col; }
    else if (slot < 21) { P = t6; oIdx = 7; col = 4 * (slot - 17); feat = 116 + col; }
    else if (slot < 25) { oIdx = 1; col = 4 * (slot - 21); feat = 20 + col; }  // lang LDS
    else if (slot < 29) { oIdx = 3; col = 4 * (slot - 25); feat = 52 + col; }  // os LDS
    else                { oIdx = 2; col = 4 * (slot - 29); feat = 36 + col; }  // plat LDS
    const bool isG = (slot < 21);

    // ---- gather: 8-deep batches over neighbor pairs ---------------------
    vf4 acc  = {0.f, 0.f, 0.f, 0.f};
    vf4 acc2 = {0.f, 0.f, 0.f, 0.f};
    const int passes = (cnt + 1) >> 1;            // <= 32
    for (int pc = 0; pc < passes; pc += 8) {
        int o[8];
        #pragma unroll
        for (int j = 0; j < 8; ++j)
            o[j] = ofs[w][2 * (pc + j) + kk][oIdx];   // pc+j <= 31 always
        if (isG) {
            vf4 val[8];
            #pragma unroll
            for (int j = 0; j < 8; ++j) {
                const float* ap = P + o[j] + col;
                asm volatile("global_load_dwordx4 %0, %1, off"
                             : "=v"(val[j]) : "v"(ap) : "memory");
            }
            asm volatile("s_waitcnt vmcnt(0)" ::: "memory");
            __builtin_amdgcn_sched_barrier(0);
            #pragma unroll
            for (int j = 0; j < 8; ++j) {
                const float m = (2 * (pc + j) + kk < cnt) ? 1.f : 0.f;
                acc[0] = fmaf(m, val[j][0], acc[0]);
                acc[1] = fmaf(m, val[j][1], acc[1]);
                acc[2] = fmaf(m, val[j][2], acc[2]);
                acc[3] = fmaf(m, val[j][3], acc[3]);
            }
        } else {
            #pragma unroll
            for (int j = 0; j < 8; ++j) {
                const float m = (2 * (pc + j) + kk < cnt) ? 1.f : 0.f;
                const float4 lv = *(const float4*)&lds_tab[o[j] + col];
                acc[0] = fmaf(m, lv.x, acc[0]);
                acc[1] = fmaf(m, lv.y, acc[1]);
                acc[2] = fmaf(m, lv.z, acc[2]);
                acc[3] = fmaf(m, lv.w, acc[3]);
                if (slot == 29) {                      // plat cols 12..15
                    const float4 l2 = *(const float4*)&lds_tab[o[j] + 12];
                    acc2[0] = fmaf(m, l2.x, acc2[0]);
                    acc2[1] = fmaf(m, l2.y, acc2[1]);
                    acc2[2] = fmaf(m, l2.z, acc2[2]);
                    acc2[3] = fmaf(m, l2.w, acc2[3]);
                }
            }
        }
    }

    // ---- pair-combine (L <-> L^32) --------------------------------------
    acc[0] += __shfl_xor(acc[0], 32, 64);
    acc[1] += __shfl_xor(acc[1], 32, 64);
    acc[2] += __shfl_xor(acc[2], 32, 64);
    acc[3] += __shfl_xor(acc[3], 32, 64);
    if (slot == 29) {
        acc2[0] += __shfl_xor(acc2[0], 32, 64);
        acc2[1] += __shfl_xor(acc2[1], 32, 64);
        acc2[2] += __shfl_xor(acc2[2], 32, 64);
        acc2[3] += __shfl_xor(acc2[3], 32, 64);
    }

    // ---- stores: 512B coalesced + one extra lane ------------------------
    if (L < 32)
        *(float4*)(fsum_ws + (size_t)item * IN2 + feat) =
            make_float4(acc[0], acc[1], acc[2], acc[3]);
    if (L == 29)
        *(float4*)(fsum_ws + (size_t)item * IN2 + 48) =
            make_float4(acc2[0], acc2[1], acc2[2], acc2[3]);
}

// ---------------------------------------------------------------------------
// K2: all dense math for 32 b-rows (16 vertices) per block, 256 threads.
// ---------------------------------------------------------------------------
__global__ __launch_bounds__(256) void gconv_dense(
    const float* __restrict__ channel_dense,
    const float* __restrict__ channel_id_emb,
    const float* __restrict__ W_agg,  const float* __restrict__ b_agg,
    const float* __restrict__ W_self, const float* __restrict__ b_self,
    const float* __restrict__ W_attn, const float* __restrict__ b_attn,
    const float* __restrict__ W_attn2,
    const int* __restrict__ channel_ids,
    const int* __restrict__ vertices,
    const int* __restrict__ bot_counts,
    const int* __restrict__ normal_counts,
    const float* __restrict__ fsum_ws,
    float* __restrict__ out)
{
    const int blk = blockIdx.x;
    const int b0  = blk * RB;
    const int v0  = blk * VB;
    const int t   = threadIdx.x;

    __shared__ alignas(16) float fs[RB][IN2];
    __shared__ alignas(16) float chvs[VB][IN1];
    __shared__ alignas(16) float hs[RB][H2];
    __shared__ float u_lds[AH][RB + 1];
    __shared__ float sarr[RB];
    __shared__ float cinv[RB];

    for (int idx = t; idx < RB * IN2 / 4; idx += 256) {
        const float4 vv = *(const float4*)(fsum_ws + (size_t)b0 * IN2 + idx * 4);
        *(float4*)&((float*)fs)[idx * 4] = vv;
    }
    if (t < RB) {
        const int b = b0 + t;
        const int v = b >> 1;
        int c = (b & 1) ? normal_counts[v] : bot_counts[v];
        c = (c > KNB) ? KNB : ((c < 1) ? 1 : c);
        cinv[t] = 1.0f / (float)c;
    }
    if (t < 128) {
        const int vx = t >> 3, q = t & 7;
        const int vert = vertices[v0 + vx];
        const float* src = (q < 4)
            ? channel_dense  + (size_t)vert * CHD + q * 4
            : channel_id_emb + (size_t)channel_ids[vert] * EMB + (q - 4) * 4;
        *(float4*)&chvs[vx][q * 4] = *(const float4*)src;
    }
    __syncthreads();

    {
        const int w = t >> 6, lane = t & 63;
        const int r0 = w * 8;
        float acc[8] = {0.f, 0.f, 0.f, 0.f, 0.f, 0.f, 0.f, 0.f};
        #pragma unroll 4
        for (int f = 0; f < IN2; ++f) {
            const float wv = W_agg[f * H2 + lane];
            #pragma unroll
            for (int r = 0; r < 8; ++r)
                acc[r] = fmaf(fs[r0 + r][f], wv, acc[r]);
        }
        const float bb = b_agg[lane];
        #pragma unroll
        for (int r = 0; r < 8; ++r)
            hs[r0 + r][lane] = fmaf(acc[r], cinv[r0 + r], bb);
    }
    __syncthreads();

    if (t < 2 * AH) {
        const int rg = (t >= AH) ? 1 : 0;
        const int aa = t - AH * rg;
        const int r0 = rg * 16;
        float acc[16];
        #pragma unroll
        for (int r = 0; r < 16; ++r) acc[r] = 0.f;
        #pragma unroll 2
        for (int f = 0; f < H2; ++f) {
            const float wv = W_attn[f * AH + aa];
            #pragma unroll
            for (int r = 0; r < 16; ++r)
                acc[r] = fmaf(hs[r0 + r][f], wv, acc[r]);
        }
        #pragma unroll 2
        for (int f = 0; f < IN1; ++f) {
            const float wv = W_attn[(H2 + f) * AH + aa];
            #pragma unroll
            for (int r = 0; r < 16; ++r)
                acc[r] = fmaf(chvs[(r0 + r) >> 1][f], wv, acc[r]);
        }
        const float ba = b_attn[aa], w2 = W_attn2[aa];
        #pragma unroll
        for (int r = 0; r < 16; ++r)
            u_lds[aa][r0 + r] = fmaxf(acc[r] + ba, 0.f) * w2;
    }
    __syncthreads();

    if (t < RB) {
        float s = 0.f;
        #pragma unroll 4
        for (int aa = 0; aa < AH; ++aa) s += u_lds[aa][t];
        sarr[t] = s;
    }
    __syncthreads();

    {
        const int vl = t >> 4;
        const int c8 = (t & 15) * 8;
        const float s0 = sarr[2 * vl], s1 = sarr[2 * vl + 1];
        const float mm = fmaxf(s0, s1);
        const float e0 = __expf(s0 - mm), e1 = __expf(s1 - mm);
        const float rs = 1.0f / (e0 + e1);
        const float a0 = e0 * rs, a1 = e1 * rs;
        float o[8];
        if (c8 < H2) {
            #pragma unroll
            for (int c = 0; c < 8; ++c)
                o[c] = fmaxf(a0 * hs[2 * vl][c8 + c] + a1 * hs[2 * vl + 1][c8 + c], 0.f);
        } else {
            const int cs = c8 - H2;
            float accS[8];
            #pragma unroll
            for (int c = 0; c < 8; ++c) accS[c] = b_self[cs + c];
            #pragma unroll 4
            for (int f = 0; f < IN1; ++f) {
                const float xv = chvs[vl][f];
                const float4 wa = *(const float4*)(W_self + f * H1 + cs);
                const float4 wb = *(const float4*)(W_self + f * H1 + cs + 4);
                accS[0] = fmaf(xv, wa.x, accS[0]);
                accS[1] = fmaf(xv, wa.y, accS[1]);
                accS[2] = fmaf(xv, wa.z, accS[2]);
                accS[3] = fmaf(xv, wa.w, accS[3]);
                accS[4] = fmaf(xv, wb.x, accS[4]);
                accS[5] = fmaf(xv, wb.y, accS[5]);
                accS[6] = fmaf(xv, wb.z, accS[6]);
                accS[7] = fmaf(xv, wb.w, accS[7]);
            }
            #pragma unroll
            for (int c = 0; c < 8; ++c) o[c] = fmaxf(accS[c], 0.f);
        }
        float4* op = (float4*)(out + (size_t)(v0 + vl) * (H1 + H2) + c8);
        op[0] = make_float4(o[0], o[1], o[2], o[3]);
        op[1] = make_float4(o[4], o[5], o[6], o[7]);
    }
}

extern "C" void kernel_launch(void* const* d_in, const int* in_sizes, int n_in,
                              void* d_out, int out_size, void* d_ws, size_t ws_size,
                              hipStream_t stream) {
    const float* channel_dense  = (const float*)d_in[0];
    const float* device_dense   = (const float*)d_in[1];
    const float* channel_id_emb = (const float*)d_in[2];
    const float* lang_emb       = (const float*)d_in[3];
    const float* plat_emb       = (const float*)d_in[4];
    const float* os_emb         = (const float*)d_in[5];
    const float* country_emb    = (const float*)d_in[6];
    const float* carrier_emb    = (const float*)d_in[7];
    const float* brand_emb      = (const float*)d_in[8];
    const float* plat_os_emb    = (const float*)d_in[9];
    const float* W_agg          = (const float*)d_in[10];
    const float* b_agg          = (const float*)d_in[11];
    const float* W_self         = (const float*)d_in[12];
    const float* b_self         = (const float*)d_in[13];
    const float* W_attn         = (const float*)d_in[14];
    const float* b_attn         = (const float*)d_in[15];
    const float* W_attn2        = (const float*)d_in[16];
    // d_in[17] = b_attn2: zero + cancels in 2-way softmax, unused
    const int* channel_ids   = (const int*)d_in[18];
    const int* device_cat    = (const int*)d_in[19];
    const int* vertices      = (const int*)d_in[20];
    const int* bot_neibrs    = (const int*)d_in[21];
    const int* normal_neibrs = (const int*)d_in[22];
    const int* bot_counts    = (const int*)d_in[23];
    const int* normal_counts = (const int*)d_in[24];

    float* fsum_ws = (float*)d_ws;   // [16384][132] = 8.65 MB
    float* out     = (float*)d_out;

    gconv_gather<<<dim3(2 * BATCH / 4), dim3(256), 0, stream>>>(
        device_dense, lang_emb, plat_emb, os_emb, country_emb, carrier_emb,
        brand_emb, plat_os_emb, device_cat, bot_neibrs, normal_neibrs,
        bot_counts, normal_counts, fsum_ws);

    gconv_dense<<<dim3(2 * BATCH / RB), dim3(256), 0, stream>>>(
        channel_dense, channel_id_emb, W_agg, b_agg, W_self, b_self,
        W_attn, b_attn, W_attn2, channel_ids, vertices,
        bot_counts, normal_counts, fsum_ws, out);
}